// Round 3
// baseline (389.598 us; speedup 1.0000x reference)
//
#include <hip/hip_runtime.h>

#define IMH 512
#define IMW 512

// ---------------------------------------------------------------------------
// Fully fused LOI kernel. Block = one combo (b*6 + s*3 + c) x 32x8 output
// tile. The 9x9 sigma smooth is recomputed per block as a separable 9+9 tap
// (Gaussian kernels are exact outer products; the 1D factor equals the 2D
// kernel's row sums). Stages (LDS): clipped image tile 22x46 -> vertical
// 9-tap (14x46) -> horizontal 9-tap (14x38 smooth tile) -> fused RBF +
// separable 7x7 alpha conv -> 24 scalar stores/thread, n-contiguous.
//
// BOUNDARY SEMANTICS (bug fixed in R3): the reference zero-pads ISO (not
// smooth) for the alpha conv. iso values at out-of-image positions must be
// exactly 0, even though the extended smooth tile is nonzero there. Row
// validity is folded into the per-tap weights; column validity is a 0/1
// multiplier on the exp.
//
// Thread map: n = t&7 (bin -> innermost output dim), r = t>>3:
//   xr = r&3 (8-px x-run), yr = r>>2 (row 0..7).
// ---------------------------------------------------------------------------
__global__ __launch_bounds__(256) void loi_fused(
    const float* __restrict__ im,      // [512][512][3]
    const float* __restrict__ sigk,    // [2][9][9]
    const float* __restrict__ alphak,  // [3][7][7]
    const float* __restrict__ binc,    // [8]
    const float* __restrict__ betas,   // [2]
    float* __restrict__ out)           // [36][512][512][8]
{
  const int t     = threadIdx.x;
  const int n     = t & 7;
  const int r     = t >> 3;
  const int xr    = r & 3;
  const int yr    = r >> 2;
  const int combo = blockIdx.z;        // b*6 + s*3 + c
  const int b     = combo / 6;
  const int sc    = combo % 6;
  const int s     = sc / 3;
  const int c     = sc % 3;
  const int tx0   = blockIdx.x * 32;
  const int ty0   = blockIdx.y * 8;

  __shared__ __align__(16) float imt[22 * 48];  // image rows ty0-7..+14, cols tx0-7..+38
  __shared__ __align__(16) float svt[14 * 48];  // vertically smoothed
  __shared__ __align__(16) float sm [14 * 40];  // smooth tile, cols tx0-3..+34
  __shared__ float kf[3][8];                    // alpha 1D factors
  __shared__ float sf[12];                      // sigma 1D factors (9 used)

  // --- stage clipped image tile (zero outside image) ---
  for (int e = t; e < 1056; e += 256) {
    int j = e / 48, i = e - j * 48;
    float v = 0.f;
    if (i < 46) {
      int gy = ty0 + j - 7, gx = tx0 + i - 7;
      if (gy >= 0 && gy < IMH && gx >= 0 && gx < IMW) {
        v = im[(gy * IMW + gx) * 3 + c];
        v = fminf(fmaxf(v, 0.f), 1.f);           // clip(im, 0, 1)
      }
    }
    imt[e] = v;
  }
  // --- 1D separable factors (row sums of the 2D kernels) ---
  if (t < 9) {
    float acc = 0.f;
    #pragma unroll
    for (int j = 0; j < 9; j++) acc += sigk[s * 81 + t * 9 + j];
    sf[t] = acc;
  }
  if (t >= 32 && t < 56) {
    int a = (t - 32) >> 3, d = t & 7;
    float v = 0.f;
    if (d < 7) {
      #pragma unroll
      for (int j = 0; j < 7; j++) v += alphak[a * 49 + d * 7 + j];
    }
    kf[a][d] = v;
  }
  __syncthreads();

  // --- vertical 9-tap sigma smooth: rows 0..13 (smooth ty0-3..+10), cols 0..45
  for (int e = t; e < 672; e += 256) {
    int rr = e / 48, i = e - rr * 48;
    if (i < 46) {
      float acc = 0.f;
      #pragma unroll
      for (int d = 0; d < 9; d++) acc = fmaf(sf[d], imt[(rr + d) * 48 + i], acc);
      svt[e] = acc;
    }
  }
  __syncthreads();

  // --- horizontal 9-tap: smooth cols 0..37 (tx0-3..tx0+34) ---
  for (int e = t; e < 560; e += 256) {
    int rr = e / 40, j = e - rr * 40;
    if (j < 38) {
      float acc = 0.f;
      #pragma unroll
      for (int d = 0; d < 9; d++) acc = fmaf(sf[d], svt[rr * 48 + j + d], acc);
      sm[e] = acc;
    }
  }
  __syncthreads();

  // --- RBF + separable 7x7 alpha conv ---
  const float beta = betas[b];
  const float sqn  = sqrtf(0.39894228040143268f / beta);     // sqrt(1/(sqrt(2pi)*b))
  const float c2   = -0.72134752044448170f / (beta * beta);  // -0.5*log2(e)/b^2
  const float ctr  = binc[n];

  float kn0[7], kn1[7], kn2[7];   // sqrt(norm) folded into each 1D pass
  #pragma unroll
  for (int d = 0; d < 7; d++) {
    kn0[d] = kf[0][d] * sqn;
    kn1[d] = kf[1][d] * sqn;
    kn2[d] = kf[2][d] * sqn;
  }

  // column validity: iso col X' = tx0 + xr*8 + i - 3 must be in [0,512)
  const int xb = tx0 + xr * 8 - 3;
  float colv[14];
  #pragma unroll
  for (int i = 0; i < 14; i++) {
    int X = xb + i;
    colv[i] = (X >= 0 && X < IMW) ? 1.f : 0.f;
  }

  float tv0[14], tv1[14], tv2[14];
  #pragma unroll
  for (int i = 0; i < 14; i++) { tv0[i] = 0.f; tv1[i] = 0.f; tv2[i] = 0.f; }

  const float* smp = sm + yr * 40 + xr * 8;
  const int yb = ty0 + yr - 3;
  #pragma unroll
  for (int d = 0; d < 7; d++) {
    const float* row = smp + d * 40;
    float4 q0 = *(const float4*)(row);
    float4 q1 = *(const float4*)(row + 4);
    float4 q2 = *(const float4*)(row + 8);
    float2 q3 = *(const float2*)(row + 12);
    float rv[14] = {q0.x, q0.y, q0.z, q0.w, q1.x, q1.y, q1.z, q1.w,
                    q2.x, q2.y, q2.z, q2.w, q3.x, q3.y};
    // row validity: iso row Y' = ty0 + yr + d - 3 must be in [0,512)
    int Y = yb + d;
    float rowm = (Y >= 0 && Y < IMH) ? 1.f : 0.f;
    float w0 = kn0[d] * rowm, w1 = kn1[d] * rowm, w2 = kn2[d] * rowm;
    #pragma unroll
    for (int i = 0; i < 14; i++) {
      float tt = rv[i] - ctr;
      float e  = exp2f(tt * tt * c2) * colv[i];
      tv0[i] = fmaf(w0, e, tv0[i]);
      tv1[i] = fmaf(w1, e, tv1[i]);
      tv2[i] = fmaf(w2, e, tv2[i]);
    }
  }

  const int gy  = ty0 + yr;
  const int gx0 = tx0 + xr * 8;
  size_t pb = ((size_t)gy * 512 + gx0) * 8 + n;
  // out plane (a, combo) = a*12 + combo; plane stride 512*512*8 = 2^21
  float* op0 = out + ((size_t)combo << 21) + pb;
  float* op1 = op0 + ((size_t)12 << 21);
  float* op2 = op1 + ((size_t)12 << 21);
  #pragma unroll
  for (int x = 0; x < 8; x++) {
    float v0 = 0.f, v1 = 0.f, v2 = 0.f;
    #pragma unroll
    for (int d = 0; d < 7; d++) {
      v0 = fmaf(kn0[d], tv0[x + d], v0);
      v1 = fmaf(kn1[d], tv1[x + d], v1);
      v2 = fmaf(kn2[d], tv2[x + d], v2);
    }
    op0[x * 8] = v0;
    op1[x * 8] = v1;
    op2[x * 8] = v2;
  }
}

extern "C" void kernel_launch(void* const* d_in, const int* in_sizes, int n_in,
                              void* d_out, int out_size, void* d_ws, size_t ws_size,
                              hipStream_t stream)
{
  const float* im   = (const float*)d_in[0];   // (512,512,3)
  const float* sigk = (const float*)d_in[1];   // (2,9,9)
  const float* alpk = (const float*)d_in[2];   // (3,7,7)
  const float* binc = (const float*)d_in[3];   // (8,)
  const float* bets = (const float*)d_in[4];   // (2,)
  float* out = (float*)d_out;                  // (3,2,2,3,512,512,8)

  loi_fused<<<dim3(16, 64, 12), 256, 0, stream>>>(im, sigk, alpk, binc, bets, out);
}